// Round 3
// baseline (219.007 us; speedup 1.0000x reference)
//
#include <hip/hip_runtime.h>

// Problem constants (from reference):
//   B=4, T=16, H=32, D=128, L=4096, HALF=64
// Inputs (setup_inputs order):
//   0: k_new  [B,T,H,D]  f32
//   1: v_new  [B,T,H,D]  f32
//   2: cos    [L,HALF]   f32
//   3: sin    [L,HALF]   f32
//   4: cache_k [B,L,H,D] f32
//   5: cache_v [B,L,H,D] f32
//   6: positions [B,T]   i32
// Output: [2, B, L, H, D] f32 — stack(out_k, out_v)

#define B 4
#define T 16
#define H 32
#define D 128
#define L 4096
#define HALF 64

// Native clang vector type — required by __builtin_nontemporal_* (HIP's
// float4 is a struct and is rejected).
typedef float f32x4 __attribute__((ext_vector_type(4)));

// Row = one (b, pos) slice of H*D = 4096 floats = 1024 float4s.
// n4 = float4s per cache = B*L*1024 = 16,777,216.
//
// Fused single pass: each thread iterates float4 indices i; the row index
// (i>>10) is wave-uniform (64-lane chunks never straddle a 1024 boundary).
// positions[64] sits in LDS; 16 compares decide if this row is replaced.
//   - not replaced: nontemporal streaming copy cache->out (zero reuse,
//     keep the 1 GB stream out of L2/L3).
//   - replaced: load k_new/v_new, RoPE-rotate k inline, store.
__global__ __launch_bounds__(256) void fused_rope_cache(
    const f32x4* __restrict__ cache_k,
    const f32x4* __restrict__ cache_v,
    const f32x4* __restrict__ k_new,
    const f32x4* __restrict__ v_new,
    const float* __restrict__ cos_t,
    const float* __restrict__ sin_t,
    const int* __restrict__ positions,
    f32x4* __restrict__ out,
    long n4) {
    __shared__ int s_pos[B * T];
    if (threadIdx.x < B * T) s_pos[threadIdx.x] = positions[threadIdx.x];
    __syncthreads();

    const long stride = (long)gridDim.x * blockDim.x;
    for (long i = (long)blockIdx.x * blockDim.x + threadIdx.x; i < n4; i += stride) {
        const int row = (int)(i >> 10);      // b*L + pos
        const int b   = row >> 12;           // / L
        const int pos = row & (L - 1);

        int bt = -1;
#pragma unroll
        for (int t = 0; t < T; ++t) {
            if (s_pos[b * T + t] == pos) bt = b * T + t;
        }

        if (bt < 0) {
            // streaming copy, bypass caches
            f32x4 k = __builtin_nontemporal_load(cache_k + i);
            f32x4 v = __builtin_nontemporal_load(cache_v + i);
            __builtin_nontemporal_store(k, out + i);
            __builtin_nontemporal_store(v, out + n4 + i);
        } else {
            const int r = (int)(i & 1023);            // float4 within row
            const long src = (long)bt * 1024 + r;     // float4 idx into k_new/v_new
            f32x4 k = k_new[src];
            f32x4 v = v_new[src];
            const int d = (r << 2) & (D - 1);         // element within head dim (even)
            const int p = d >> 1;                     // first pair index
            const float c0 = cos_t[pos * HALF + p];
            const float s0 = sin_t[pos * HALF + p];
            const float c1 = cos_t[pos * HALF + p + 1];
            const float s1 = sin_t[pos * HALF + p + 1];
            f32x4 kr;
            kr.x = k.x * c0 - k.y * s0;
            kr.y = k.x * s0 + k.y * c0;
            kr.z = k.z * c1 - k.w * s1;
            kr.w = k.z * s1 + k.w * c1;
            out[i] = kr;
            out[n4 + i] = v;
        }
    }
}

extern "C" void kernel_launch(void* const* d_in, const int* in_sizes, int n_in,
                              void* d_out, int out_size, void* d_ws, size_t ws_size,
                              hipStream_t stream) {
    const f32x4* k_new = (const f32x4*)d_in[0];
    const f32x4* v_new = (const f32x4*)d_in[1];
    const float* cos_t  = (const float*)d_in[2];
    const float* sin_t  = (const float*)d_in[3];
    const f32x4* ck    = (const f32x4*)d_in[4];
    const f32x4* cv    = (const f32x4*)d_in[5];
    const int* positions = (const int*)d_in[6];

    f32x4* out = (f32x4*)d_out;
    const long cache_elems = (long)B * L * H * D;   // 67,108,864 floats
    const long n4 = cache_elems / 4;                // 16,777,216 float4s per cache

    // 4096 blocks x 256 threads = 1M threads, 16 iterations each,
    // 64 B moved per thread-iteration.
    fused_rope_cache<<<4096, 256, 0, stream>>>(
        ck, cv, k_new, v_new, cos_t, sin_t, positions, out, n4);
}

// Round 4
// 206.428 us; speedup vs baseline: 1.0609x; 1.0609x over previous
//
#include <hip/hip_runtime.h>

// Problem constants (from reference):
//   B=4, T=16, H=32, D=128, L=4096, HALF=64
// Inputs (setup_inputs order):
//   0: k_new  [B,T,H,D]  f32
//   1: v_new  [B,T,H,D]  f32
//   2: cos    [L,HALF]   f32
//   3: sin    [L,HALF]   f32
//   4: cache_k [B,L,H,D] f32
//   5: cache_v [B,L,H,D] f32
//   6: positions [B,T]   i32
// Output: [2, B, L, H, D] f32 — stack(out_k, out_v)

#define B 4
#define T 16
#define H 32
#define D 128
#define L 4096
#define HALF 64

// ---------------------------------------------------------------------------
// RoPE-rotate k_new and scatter k_rot / v_new into the output at the row
// given by positions[b,t]. One thread per interleaved pair. Runs AFTER the
// bulk D2D copies on the same stream, overwriting the 64 target rows.
// Positions are unique per (b,t) -> deterministic.
// ---------------------------------------------------------------------------
__global__ void rope_scatter(const float* __restrict__ k_new,
                             const float* __restrict__ v_new,
                             const float* __restrict__ cos_t,
                             const float* __restrict__ sin_t,
                             const int* __restrict__ positions,
                             float* __restrict__ out_k,
                             float* __restrict__ out_v) {
    int idx = blockIdx.x * blockDim.x + threadIdx.x;   // [0, B*T*H*HALF)
    int p  = idx & (HALF - 1);          // pair index within head dim
    int h  = (idx >> 6) & (H - 1);      // head
    int bt = idx >> 11;                 // b*T + t
    int b  = bt >> 4;                   // /T (T=16)

    int pos = positions[bt];

    const float2 kv = *(const float2*)(k_new + (size_t)idx * 2);
    const float2 vv = *(const float2*)(v_new + (size_t)idx * 2);
    float c = cos_t[pos * HALF + p];
    float s = sin_t[pos * HALF + p];

    float2 kr;
    kr.x = kv.x * c - kv.y * s;
    kr.y = kv.x * s + kv.y * c;

    size_t dst = (((size_t)b * L + pos) * H + h) * (size_t)D + 2 * (size_t)p;
    *(float2*)(out_k + dst) = kr;
    *(float2*)(out_v + dst) = vv;
}

extern "C" void kernel_launch(void* const* d_in, const int* in_sizes, int n_in,
                              void* d_out, int out_size, void* d_ws, size_t ws_size,
                              hipStream_t stream) {
    const float* k_new  = (const float*)d_in[0];
    const float* v_new  = (const float*)d_in[1];
    const float* cos_t  = (const float*)d_in[2];
    const float* sin_t  = (const float*)d_in[3];
    const void* ck      = d_in[4];
    const void* cv      = d_in[5];
    const int* positions = (const int*)d_in[6];

    float* out = (float*)d_out;
    const size_t cache_elems = (size_t)B * L * H * D;     // 67,108,864 floats
    const size_t cache_bytes = cache_elems * sizeof(float); // 256 MiB

    // Bulk: vendor-tuned D2D copies (graph-capturable per harness contract).
    hipMemcpyAsync(out, ck, cache_bytes, hipMemcpyDeviceToDevice, stream);
    hipMemcpyAsync(out + cache_elems, cv, cache_bytes, hipMemcpyDeviceToDevice, stream);

    // Scatter: B*T*H*HALF = 131072 threads -> 512 blocks x 256.
    const int n_pairs = B * T * H * HALF;
    rope_scatter<<<n_pairs / 256, 256, 0, stream>>>(
        k_new, v_new, cos_t, sin_t, positions,
        out, out + cache_elems);
}

// Round 5
// 200.887 us; speedup vs baseline: 1.0902x; 1.0276x over previous
//
#include <hip/hip_runtime.h>

// Problem constants (from reference):
//   B=4, T=16, H=32, D=128, L=4096, HALF=64
// Inputs (setup_inputs order):
//   0: k_new  [B,T,H,D]  f32
//   1: v_new  [B,T,H,D]  f32
//   2: cos    [L,HALF]   f32
//   3: sin    [L,HALF]   f32
//   4: cache_k [B,L,H,D] f32
//   5: cache_v [B,L,H,D] f32
//   6: positions [B,T]   i32
// Output: [2, B, L, H, D] f32 — stack(out_k, out_v)

#define B 4
#define T 16
#define H 32
#define D 128
#define L 4096
#define HALF 64

typedef float f32x4 __attribute__((ext_vector_type(4)));

// ---------------------------------------------------------------------------
// Batched copy: each block owns a contiguous 2048-float4 (32 KiB) chunk of
// the flat [cache_k ; cache_v] space. Each thread loads 8 independent
// dwordx4 (128 B in flight), THEN stores 8 — long read bursts / long write
// bursts instead of per-instruction read-write alternation.
// Chunks never straddle the k/v boundary (n4 % 2048 == 0), so the source
// pointer select is block-uniform.
// ---------------------------------------------------------------------------
#define CHUNK 2048   // float4s per block = blockDim(256) * PER_THREAD(8)
#define PER_THREAD 8

__global__ __launch_bounds__(256) void copy_caches_batched(
    const f32x4* __restrict__ cache_k,
    const f32x4* __restrict__ cache_v,
    f32x4* __restrict__ out,
    long n4) {
    const long flat0 = (long)blockIdx.x * CHUNK;           // block's first float4
    const bool second = flat0 >= n4;                        // block-uniform
    const f32x4* __restrict__ src = second ? cache_v : cache_k;
    const long srcoff = second ? (flat0 - n4) : flat0;

    const int t = threadIdx.x;
    f32x4 r[PER_THREAD];
#pragma unroll
    for (int j = 0; j < PER_THREAD; ++j)
        r[j] = src[srcoff + t + j * 256];
#pragma unroll
    for (int j = 0; j < PER_THREAD; ++j)
        out[flat0 + t + j * 256] = r[j];
}

// ---------------------------------------------------------------------------
// RoPE-rotate k_new and scatter k_rot / v_new into the output at the row
// given by positions[b,t]. One thread per interleaved pair. Runs AFTER the
// bulk copy on the same stream, overwriting the 64 target rows.
// ---------------------------------------------------------------------------
__global__ void rope_scatter(const float* __restrict__ k_new,
                             const float* __restrict__ v_new,
                             const float* __restrict__ cos_t,
                             const float* __restrict__ sin_t,
                             const int* __restrict__ positions,
                             float* __restrict__ out_k,
                             float* __restrict__ out_v) {
    int idx = blockIdx.x * blockDim.x + threadIdx.x;   // [0, B*T*H*HALF)
    int p  = idx & (HALF - 1);          // pair index within head dim
    int h  = (idx >> 6) & (H - 1);      // head
    int bt = idx >> 11;                 // b*T + t
    int b  = bt >> 4;                   // /T (T=16)

    int pos = positions[bt];

    const float2 kv = *(const float2*)(k_new + (size_t)idx * 2);
    const float2 vv = *(const float2*)(v_new + (size_t)idx * 2);
    float c = cos_t[pos * HALF + p];
    float s = sin_t[pos * HALF + p];

    float2 kr;
    kr.x = kv.x * c - kv.y * s;
    kr.y = kv.x * s + kv.y * c;

    size_t dst = (((size_t)b * L + pos) * H + h) * (size_t)D + 2 * (size_t)p;
    *(float2*)(out_k + dst) = kr;
    *(float2*)(out_v + dst) = vv;
}

extern "C" void kernel_launch(void* const* d_in, const int* in_sizes, int n_in,
                              void* d_out, int out_size, void* d_ws, size_t ws_size,
                              hipStream_t stream) {
    const float* k_new  = (const float*)d_in[0];
    const float* v_new  = (const float*)d_in[1];
    const float* cos_t  = (const float*)d_in[2];
    const float* sin_t  = (const float*)d_in[3];
    const f32x4* ck     = (const f32x4*)d_in[4];
    const f32x4* cv     = (const f32x4*)d_in[5];
    const int* positions = (const int*)d_in[6];

    float* out = (float*)d_out;
    const long cache_elems = (long)B * L * H * D;   // 67,108,864 floats
    const long n4 = cache_elems / 4;                // 16,777,216 float4s per cache

    // 2 * n4 / CHUNK = 16384 blocks, 256 threads, 8 float4s each, one shot.
    const int nblocks = (int)(2 * n4 / CHUNK);
    copy_caches_batched<<<nblocks, 256, 0, stream>>>(ck, cv, (f32x4*)out, n4);

    // Scatter: B*T*H*HALF = 131072 threads -> 512 blocks x 256.
    const int n_pairs = B * T * H * HALF;
    rope_scatter<<<n_pairs / 256, 256, 0, stream>>>(
        k_new, v_new, cos_t, sin_t, positions,
        out, out + cache_elems);
}